// Round 7
// baseline (1175.589 us; speedup 1.0000x reference)
//
#include <hip/hip_runtime.h>
#include <hip/hip_cooperative_groups.h>

namespace cg = cooperative_groups;

#define C 64
#define SCAN_ELEMS 2048   // 256 threads x 8 elements per scan chunk

typedef float f4 __attribute__((ext_vector_type(4)));

// ---------------------------------------------------------------------------
// ONE cooperative kernel, 7 phases separated by grid.sync():
//  1. zero:   counts[n_vox] = 0
//  2. hist:   counts[v]++ per point            (int atomics, L2-resident)
//  3. reduce: chunk b (2048 voxels) -> agg[b]; local scan kept in registers
//  4. scan:   block 0 exclusive-scans agg[0..nb) (nb <= 256)
//  5. apply:  offsets/cursor written from agg[b] + register-resident locals
//  6. fill:   plist[atomicAdd(cursor[v])] = pid (CSR point lists)
//  7. fused:  16 threads/voxel (4ch each), 3-deep software-pipelined loop:
//             nt-load p_feats row -> gate MLP (DPP shfl reduce) -> softmax ->
//             nt-store fuse row + reg accumulate -> v_new = acc/max(cnt,1)
// Removes 4 graph-node gaps; gives full rocprof attribution to one dispatch.
// ---------------------------------------------------------------------------

__global__ __launch_bounds__(256) void mega_kernel(
    const float* __restrict__ p_feats, const float* __restrict__ v_feats,
    const float* __restrict__ Wp, const float* __restrict__ bp,
    const float* __restrict__ Wv, const float* __restrict__ bv,
    const int* __restrict__ p2v,
    float* __restrict__ fuse_out, float* __restrict__ v_new,
    int* __restrict__ counts, int* __restrict__ agg,
    int* __restrict__ offsets, int* __restrict__ cursor,
    int* __restrict__ plist,
    int n_pts, int n_vox, int nb)
{
    cg::grid_group grid = cg::this_grid();
    const int tid = threadIdx.x;
    const int b = blockIdx.x;
    const int T_all = gridDim.x * blockDim.x;
    const int gtid = b * blockDim.x + tid;

    // ---- phase 1: zero counts ----
    for (int i = gtid; i < n_vox; i += T_all) counts[i] = 0;
    grid.sync();

    // ---- phase 2: histogram ----
    for (int i = gtid; i < n_pts; i += T_all) atomicAdd(&counts[p2v[i]], 1);
    grid.sync();

    // ---- phase 3: per-chunk reduce + local scan (block b owns chunk b) ----
    int vals[8];
    int sloc = 0, incl = 0, wbase = 0;
    __shared__ int wsum[4];
    __shared__ int sh[256];
    if (b < nb) {
        const int i0 = b * SCAN_ELEMS + tid * 8;
        #pragma unroll
        for (int j = 0; j < 8; j++) {
            int idx = i0 + j;
            vals[j] = (idx < n_vox) ? counts[idx] : 0;
        }
        #pragma unroll
        for (int j = 0; j < 8; j++) sloc += vals[j];

        const int lane = tid & 63, wave = tid >> 6;
        incl = sloc;
        #pragma unroll
        for (int off = 1; off < 64; off <<= 1) {
            int t = __shfl_up(incl, off);
            if (lane >= off) incl += t;
        }
        if (lane == 63) wsum[wave] = incl;
        __syncthreads();
        wbase = 0;
        #pragma unroll
        for (int w = 0; w < 4; w++) wbase += (w < wave) ? wsum[w] : 0;
        if (tid == 0) agg[b] = wsum[0] + wsum[1] + wsum[2] + wsum[3];
    }
    grid.sync();

    // ---- phase 4: block 0 exclusive-scans agg[0..nb) (nb <= 256) ----
    if (b == 0) {
        const int v = (tid < nb) ? agg[tid] : 0;
        sh[tid] = v;
        __syncthreads();
        #pragma unroll
        for (int off = 1; off < 256; off <<= 1) {
            int t = (tid >= off) ? sh[tid - off] : 0;
            __syncthreads();
            sh[tid] += t;
            __syncthreads();
        }
        if (tid < nb) agg[tid] = sh[tid] - v;     // exclusive prefix
        if (tid == 0) offsets[n_vox] = sh[255];   // total = n_pts
    }
    grid.sync();

    // ---- phase 5: write offsets & cursor from register-resident locals ----
    if (b < nb) {
        int run = agg[b] + wbase + (incl - sloc);
        const int i0 = b * SCAN_ELEMS + tid * 8;
        #pragma unroll
        for (int j = 0; j < 8; j++) {
            int idx = i0 + j;
            if (idx < n_vox) { offsets[idx] = run; cursor[idx] = run; }
            run += vals[j];
        }
    }
    grid.sync();

    // ---- phase 6: fill CSR point lists ----
    for (int i = gtid; i < n_pts; i += T_all) {
        int v = p2v[i];
        int pos = atomicAdd(&cursor[v], 1);
        plist[pos] = i;
    }
    grid.sync();

    // ---- phase 7: fused gather / gate MLP / softmax / fuse / scatter-mean ----
    {
        const int t = tid & 15;              // 4 channels per thread
        const int nGroups = T_all >> 4;      // 16-thread groups in the grid
        const int g0 = gtid >> 4;

        const f4* Wp4 = (const f4*)Wp;
        const f4* Wv4 = (const f4*)Wv;
        const f4 wpA = Wp4[2 * t], wpB = Wp4[2 * t + 1];
        const f4 wvA = Wv4[2 * t], wvB = Wv4[2 * t + 1];
        const float bias0 = bp[0] + bv[0];
        const float bias1 = bp[1] + bv[1];

        for (int v = g0; v < n_vox; v += nGroups) {
            const f4 vf = *(const f4*)(v_feats + (size_t)v * C + t * 4);

            float lv0 = vf.x * wvA.x + vf.y * wvA.z + vf.z * wvB.x + vf.w * wvB.z;
            float lv1 = vf.x * wvA.y + vf.y * wvA.w + vf.z * wvB.y + vf.w * wvB.w;
            #pragma unroll
            for (int m = 1; m < 16; m <<= 1) {
                lv0 += __shfl_xor(lv0, m);
                lv1 += __shfl_xor(lv1, m);
            }
            lv0 += bias0;
            lv1 += bias1;

            const int beg = offsets[v];
            const int n = offsets[v + 1] - beg;
            f4 acc = (f4){0.f, 0.f, 0.f, 0.f};

            // 3-deep software pipeline; nontemporal on zero-reuse streams
            int pidA = 0, pidB = 0, pidC = 0;
            f4 pfA = (f4){0.f, 0.f, 0.f, 0.f}, pfB = pfA, pfC = pfA;
            if (n > 0) {
                pidA = plist[beg];
                pfA = __builtin_nontemporal_load((const f4*)(p_feats + (size_t)pidA * C + t * 4));
            }
            if (n > 1) {
                pidB = plist[beg + 1];
                pfB = __builtin_nontemporal_load((const f4*)(p_feats + (size_t)pidB * C + t * 4));
            }
            if (n > 2) {
                pidC = plist[beg + 2];
                pfC = __builtin_nontemporal_load((const f4*)(p_feats + (size_t)pidC * C + t * 4));
            }

            for (int i = 0; i < n; i++) {
                const int pid = pidA;
                const f4 pf = pfA;
                pidA = pidB; pfA = pfB;
                pidB = pidC; pfB = pfC;
                if (i + 3 < n) {
                    pidC = plist[beg + i + 3];
                    pfC = __builtin_nontemporal_load((const f4*)(p_feats + (size_t)pidC * C + t * 4));
                }

                float l0 = pf.x * wpA.x + pf.y * wpA.z + pf.z * wpB.x + pf.w * wpB.z;
                float l1 = pf.x * wpA.y + pf.y * wpA.w + pf.z * wpB.y + pf.w * wpB.w;
                #pragma unroll
                for (int m = 1; m < 16; m <<= 1) {
                    l0 += __shfl_xor(l0, m);
                    l1 += __shfl_xor(l1, m);
                }
                l0 += lv0;
                l1 += lv1;

                const float mx = fmaxf(l0, l1);
                const float e0 = __expf(l0 - mx), e1 = __expf(l1 - mx);
                const float w0 = e0 / (e0 + e1);
                const float w1 = 1.0f - w0;

                f4 f;
                f.x = pf.x * w0 + vf.x * w1;
                f.y = pf.y * w0 + vf.y * w1;
                f.z = pf.z * w0 + vf.z * w1;
                f.w = pf.w * w0 + vf.w * w1;

                __builtin_nontemporal_store(f, (f4*)(fuse_out + (size_t)pid * C + t * 4));
                acc.x += f.x; acc.y += f.y; acc.z += f.z; acc.w += f.w;
            }

            const float inv = 1.0f / (float)max(n, 1);
            f4 r;
            r.x = acc.x * inv; r.y = acc.y * inv; r.z = acc.z * inv; r.w = acc.w * inv;
            *(f4*)(v_new + (size_t)v * C + t * 4) = r;
        }
    }
}

extern "C" void kernel_launch(void* const* d_in, const int* in_sizes, int n_in,
                              void* d_out, int out_size, void* d_ws, size_t ws_size,
                              hipStream_t stream) {
    const float* p_feats = (const float*)d_in[0];
    const float* v_feats = (const float*)d_in[1];
    const float* Wp = (const float*)d_in[2];
    const float* bp = (const float*)d_in[3];
    const float* Wv = (const float*)d_in[4];
    const float* bv = (const float*)d_in[5];
    const int* p2v = (const int*)d_in[6];

    int n_pts = in_sizes[0] / C;
    int n_vox = in_sizes[1] / C;
    int nb = (n_vox + SCAN_ELEMS - 1) / SCAN_ELEMS;   // 196 for 400K voxels

    float* fuse_out = (float*)d_out;
    float* v_new = fuse_out + (size_t)n_pts * C;

    // workspace (ints): [counts n_vox][agg 256][offsets n_vox+1][cursor n_vox][plist n_pts]
    int* counts = (int*)d_ws;
    int* agg = counts + n_vox;
    int* offsets = agg + 256;
    int* cursor = offsets + (n_vox + 1);
    int* plist = cursor + n_vox;

    // co-resident grid size (deterministic queries; capture-safe, no stream ops)
    int devId = 0;
    hipGetDevice(&devId);
    int numCU = 0;
    hipDeviceGetAttribute(&numCU, hipDeviceAttributeMultiprocessorCount, devId);
    int blocksPerCU = 0;
    hipOccupancyMaxActiveBlocksPerMultiprocessor(&blocksPerCU, mega_kernel, 256, 0);
    if (blocksPerCU < 1) blocksPerCU = 1;
    int G = numCU * blocksPerCU;
    if (G < nb) G = nb;   // scan needs >= nb co-resident blocks (196 << G)

    void* args[] = {
        (void*)&p_feats, (void*)&v_feats, (void*)&Wp, (void*)&bp,
        (void*)&Wv, (void*)&bv, (void*)&p2v,
        (void*)&fuse_out, (void*)&v_new,
        (void*)&counts, (void*)&agg, (void*)&offsets, (void*)&cursor,
        (void*)&plist,
        (void*)&n_pts, (void*)&n_vox, (void*)&nb
    };
    hipLaunchCooperativeKernel((const void*)mega_kernel, dim3(G), dim3(256),
                               args, 0, stream);
}

// Round 8
// 434.150 us; speedup vs baseline: 2.7078x; 2.7078x over previous
//
#include <hip/hip_runtime.h>

#define C 64

typedef float f4 __attribute__((ext_vector_type(4)));

// ---------------------------------------------------------------------------
// Fixed-capacity bucket CSR (no scan), 5 dispatches:
//  1. zero:   cnt[n_vox] + {spill_n, ovf_n} = 0
//  2. build:  r = atomicAdd(&cnt[v],1); r<K ? bucket[v*K+r]=pid
//             : (r==K ? ovf[ovf_n++]=v : 0), spill[spill_n++]=pid
//  3. fused:  16 thr/voxel (4ch each), 3-deep pipelined loop over bucket pts:
//             nt-load p row -> gate MLP (DPP shfl) -> softmax -> nt-store fuse
//             + reg accumulate; v_new = acc/max(n,1) if n<=K else raw acc
//  4. spill:  per spilled point (16 thr): compute fuse row, float-atomicAdd
//             into v_new (rare: Poisson(5) tail past K=16 ~ 1e-6 of points)
//  5. ovfdiv: divide overflow voxels' v_new by cnt
// Correct for ANY K>=1; K chosen from ws_size on host (deterministic).
// ---------------------------------------------------------------------------

__global__ __launch_bounds__(256) void zero_kernel(int* __restrict__ p, int n)
{
    int i = blockIdx.x * blockDim.x + threadIdx.x;
    if (i < n) p[i] = 0;
}

__global__ __launch_bounds__(256) void build_kernel(
    const int* __restrict__ p2v, int* __restrict__ cnt,
    int* __restrict__ bucket, int* __restrict__ spill, int* __restrict__ spill_n,
    int* __restrict__ ovf, int* __restrict__ ovf_n, int n_pts, int K)
{
    int i = blockIdx.x * blockDim.x + threadIdx.x;
    if (i >= n_pts) return;
    const int v = p2v[i];
    const int r = atomicAdd(&cnt[v], 1);
    if (r < K) {
        bucket[(size_t)v * K + r] = i;
    } else {
        if (r == K) {                 // exactly one point triggers per ovf voxel
            int o = atomicAdd(ovf_n, 1);
            ovf[o] = v;
        }
        int s = atomicAdd(spill_n, 1);
        spill[s] = i;
    }
}

__global__ __launch_bounds__(256) void fused_kernel(
    const float* __restrict__ p_feats, const float* __restrict__ v_feats,
    const float* __restrict__ Wp, const float* __restrict__ bp,
    const float* __restrict__ Wv, const float* __restrict__ bv,
    const int* __restrict__ cnt, const int* __restrict__ bucket,
    float* __restrict__ fuse_out, float* __restrict__ v_new, int n_vox, int K)
{
    const int gid = blockIdx.x * blockDim.x + threadIdx.x;
    const int v = gid >> 4;          // 16 threads per voxel
    const int t = gid & 15;          // 4 channels per thread
    if (v >= n_vox) return;

    const f4* Wp4 = (const f4*)Wp;
    const f4* Wv4 = (const f4*)Wv;
    const f4 wpA = Wp4[2 * t], wpB = Wp4[2 * t + 1];
    const f4 wvA = Wv4[2 * t], wvB = Wv4[2 * t + 1];
    const float bias0 = bp[0] + bv[0];
    const float bias1 = bp[1] + bv[1];

    const f4 vf = *(const f4*)(v_feats + (size_t)v * C + t * 4);

    float lv0 = vf.x * wvA.x + vf.y * wvA.z + vf.z * wvB.x + vf.w * wvB.z;
    float lv1 = vf.x * wvA.y + vf.y * wvA.w + vf.z * wvB.y + vf.w * wvB.w;
    #pragma unroll
    for (int m = 1; m < 16; m <<= 1) {
        lv0 += __shfl_xor(lv0, m);
        lv1 += __shfl_xor(lv1, m);
    }
    lv0 += bias0;
    lv1 += bias1;

    const int n = cnt[v];
    const int m = min(n, K);
    const size_t b0 = (size_t)v * K;
    f4 acc = (f4){0.f, 0.f, 0.f, 0.f};

    // 3-deep software pipeline over bucketed points (nt on zero-reuse streams)
    int pidA = 0, pidB = 0, pidC = 0;
    f4 pfA = (f4){0.f, 0.f, 0.f, 0.f}, pfB = pfA, pfC = pfA;
    if (m > 0) {
        pidA = bucket[b0];
        pfA = __builtin_nontemporal_load((const f4*)(p_feats + (size_t)pidA * C + t * 4));
    }
    if (m > 1) {
        pidB = bucket[b0 + 1];
        pfB = __builtin_nontemporal_load((const f4*)(p_feats + (size_t)pidB * C + t * 4));
    }
    if (m > 2) {
        pidC = bucket[b0 + 2];
        pfC = __builtin_nontemporal_load((const f4*)(p_feats + (size_t)pidC * C + t * 4));
    }

    for (int i = 0; i < m; i++) {
        const int pid = pidA;
        const f4 pf = pfA;
        pidA = pidB; pfA = pfB;
        pidB = pidC; pfB = pfC;
        if (i + 3 < m) {
            pidC = bucket[b0 + i + 3];
            pfC = __builtin_nontemporal_load((const f4*)(p_feats + (size_t)pidC * C + t * 4));
        }

        float l0 = pf.x * wpA.x + pf.y * wpA.z + pf.z * wpB.x + pf.w * wpB.z;
        float l1 = pf.x * wpA.y + pf.y * wpA.w + pf.z * wpB.y + pf.w * wpB.w;
        #pragma unroll
        for (int mm = 1; mm < 16; mm <<= 1) {
            l0 += __shfl_xor(l0, mm);
            l1 += __shfl_xor(l1, mm);
        }
        l0 += lv0;
        l1 += lv1;

        const float mx = fmaxf(l0, l1);
        const float e0 = __expf(l0 - mx), e1 = __expf(l1 - mx);
        const float w0 = e0 / (e0 + e1);
        const float w1 = 1.0f - w0;

        f4 f;
        f.x = pf.x * w0 + vf.x * w1;
        f.y = pf.y * w0 + vf.y * w1;
        f.z = pf.z * w0 + vf.z * w1;
        f.w = pf.w * w0 + vf.w * w1;

        __builtin_nontemporal_store(f, (f4*)(fuse_out + (size_t)pid * C + t * 4));
        acc.x += f.x; acc.y += f.y; acc.z += f.z; acc.w += f.w;
    }

    if (n <= K) {
        const float inv = 1.0f / (float)max(n, 1);
        f4 r;
        r.x = acc.x * inv; r.y = acc.y * inv; r.z = acc.z * inv; r.w = acc.w * inv;
        *(f4*)(v_new + (size_t)v * C + t * 4) = r;
    } else {
        // overflow voxel: store raw partial sum; spill adds rest; ovfdiv divides
        *(f4*)(v_new + (size_t)v * C + t * 4) = acc;
    }
}

__global__ __launch_bounds__(256) void spill_kernel(
    const float* __restrict__ p_feats, const float* __restrict__ v_feats,
    const float* __restrict__ Wp, const float* __restrict__ bp,
    const float* __restrict__ Wv, const float* __restrict__ bv,
    const int* __restrict__ p2v, const int* __restrict__ spill,
    const int* __restrict__ spill_n,
    float* __restrict__ fuse_out, float* __restrict__ v_new)
{
    const int sn = *spill_n;
    const int total = sn * 16;
    const int T_all = gridDim.x * blockDim.x;
    const int gtid = blockIdx.x * blockDim.x + threadIdx.x;

    for (int slot = gtid; slot < total; slot += T_all) {
        const int j = slot >> 4;      // spill entry (16 consecutive threads)
        const int t = slot & 15;      // 4 channels per thread

        const int pid = spill[j];
        const int v = p2v[pid];

        const f4* Wp4 = (const f4*)Wp;
        const f4* Wv4 = (const f4*)Wv;
        const f4 wpA = Wp4[2 * t], wpB = Wp4[2 * t + 1];
        const f4 wvA = Wv4[2 * t], wvB = Wv4[2 * t + 1];

        const f4 vf = *(const f4*)(v_feats + (size_t)v * C + t * 4);
        const f4 pf = *(const f4*)(p_feats + (size_t)pid * C + t * 4);

        float l0 = pf.x * wpA.x + pf.y * wpA.z + pf.z * wpB.x + pf.w * wpB.z
                 + vf.x * wvA.x + vf.y * wvA.z + vf.z * wvB.x + vf.w * wvB.z;
        float l1 = pf.x * wpA.y + pf.y * wpA.w + pf.z * wpB.y + pf.w * wpB.w
                 + vf.x * wvA.y + vf.y * wvA.w + vf.z * wvB.y + vf.w * wvB.w;
        #pragma unroll
        for (int m = 1; m < 16; m <<= 1) {
            l0 += __shfl_xor(l0, m);
            l1 += __shfl_xor(l1, m);
        }
        l0 += bp[0] + bv[0];
        l1 += bp[1] + bv[1];

        const float mx = fmaxf(l0, l1);
        const float e0 = __expf(l0 - mx), e1 = __expf(l1 - mx);
        const float w0 = e0 / (e0 + e1);
        const float w1 = 1.0f - w0;

        f4 f;
        f.x = pf.x * w0 + vf.x * w1;
        f.y = pf.y * w0 + vf.y * w1;
        f.z = pf.z * w0 + vf.z * w1;
        f.w = pf.w * w0 + vf.w * w1;

        *(f4*)(fuse_out + (size_t)pid * C + t * 4) = f;

        float* s = v_new + (size_t)v * C + t * 4;
        atomicAdd(s + 0, f.x);
        atomicAdd(s + 1, f.y);
        atomicAdd(s + 2, f.z);
        atomicAdd(s + 3, f.w);
    }
}

__global__ __launch_bounds__(256) void ovfdiv_kernel(
    const int* __restrict__ ovf, const int* __restrict__ ovf_n,
    const int* __restrict__ cnt, float* __restrict__ v_new)
{
    const int on = *ovf_n;
    const int total = on * 16;
    const int T_all = gridDim.x * blockDim.x;
    const int gtid = blockIdx.x * blockDim.x + threadIdx.x;

    for (int slot = gtid; slot < total; slot += T_all) {
        const int j = slot >> 4;
        const int t = slot & 15;
        const int v = ovf[j];
        const float inv = 1.0f / (float)cnt[v];
        f4* p = (f4*)(v_new + (size_t)v * C + t * 4);
        f4 x = *p;
        x.x *= inv; x.y *= inv; x.z *= inv; x.w *= inv;
        *p = x;
    }
}

extern "C" void kernel_launch(void* const* d_in, const int* in_sizes, int n_in,
                              void* d_out, int out_size, void* d_ws, size_t ws_size,
                              hipStream_t stream) {
    const float* p_feats = (const float*)d_in[0];
    const float* v_feats = (const float*)d_in[1];
    const float* Wp = (const float*)d_in[2];
    const float* bp = (const float*)d_in[3];
    const float* Wv = (const float*)d_in[4];
    const float* bv = (const float*)d_in[5];
    const int* p2v = (const int*)d_in[6];

    const int n_pts = in_sizes[0] / C;
    const int n_vox = in_sizes[1] / C;

    float* fuse_out = (float*)d_out;
    float* v_new = fuse_out + (size_t)n_pts * C;

    // bucket capacity from available workspace (deterministic: ws_size fixed)
    // layout (ints): cnt[n_vox] | spill_n | ovf_n | pad->16 | bucket[n_vox*K]
    //              | spill[n_pts] | ovf[n_vox]
    const size_t ws_ints = ws_size / sizeof(int);
    const size_t fixed = (size_t)n_vox + 16 + (size_t)n_pts + (size_t)n_vox;
    long long avail = (long long)ws_ints - (long long)fixed;
    int K = 16;
    if (avail < (long long)n_vox * K) K = (int)(avail / n_vox);
    if (K < 1) K = 1;

    int* cnt = (int*)d_ws;
    int* spill_n = cnt + n_vox;
    int* ovf_n = spill_n + 1;
    int* bucket = cnt + n_vox + 16;
    int* spill = bucket + (size_t)n_vox * K;
    int* ovf = spill + n_pts;

    const int T = 256;

    zero_kernel<<<(n_vox + 2 + T - 1) / T, T, 0, stream>>>(cnt, n_vox + 2);
    build_kernel<<<(n_pts + T - 1) / T, T, 0, stream>>>(
        p2v, cnt, bucket, spill, spill_n, ovf, ovf_n, n_pts, K);
    fused_kernel<<<((size_t)n_vox * 16 + T - 1) / T, T, 0, stream>>>(
        p_feats, v_feats, Wp, bp, Wv, bv, cnt, bucket,
        fuse_out, v_new, n_vox, K);
    spill_kernel<<<32, T, 0, stream>>>(
        p_feats, v_feats, Wp, bp, Wv, bv, p2v, spill, spill_n,
        fuse_out, v_new);
    ovfdiv_kernel<<<16, T, 0, stream>>>(ovf, ovf_n, cnt, v_new);
}